// Round 1
// baseline (57951.965 us; speedup 1.0000x reference)
//
#include <hip/hip_runtime.h>
#include <hip/hip_bf16.h>

#define LNUM 12
#define NH 8
#define DM 512
#define DHD 64
#define DFF 2048
#define NV 10000
#define QL 1024
#define ML 1024
#define BS 4
#define KL 2048   // ML+QL

static __device__ __forceinline__ float wave_sum(float v) {
#pragma unroll
    for (int o = 32; o > 0; o >>= 1) v += __shfl_xor(v, o, 64);
    return v;
}
static __device__ __forceinline__ float wave_max(float v) {
#pragma unroll
    for (int o = 32; o > 0; o >>= 1) v = fmaxf(v, __shfl_xor(v, o, 64));
    return v;
}

// h[t][c] = emb[x[t]][c] * sqrt(DM);  one float4 per thread
__global__ __launch_bounds__(256) void k_embed(const int* __restrict__ x,
                                               const float* __restrict__ emb,
                                               float* __restrict__ h) {
    int gid = blockIdx.x * 256 + threadIdx.x;  // over 4096*128 float4s
    int t = gid >> 7;
    int c4 = gid & 127;
    int tok = x[t];
    float4 e = reinterpret_cast<const float4*>(emb + (size_t)tok * DM)[c4];
    const float s = 22.62741699796952f;  // sqrt(512)
    e.x *= s; e.y *= s; e.z *= s; e.w *= s;
    reinterpret_cast<float4*>(h + (size_t)t * DM)[c4] = e;
}

// r[j][c]: pos = KL-1-j; c<256 -> sin(pos*invf[c]) ; c>=256 -> cos(pos*invf[c-256])
__global__ __launch_bounds__(256) void k_posemb(float* __restrict__ r) {
    int gid = blockIdx.x * 256 + threadIdx.x;  // over KL*DM
    int j = gid >> 9;
    int c = gid & 511;
    float pos = (float)(KL - 1 - j);
    int ci = (c < 256) ? c : (c - 256);
    float invf = powf(10000.0f, -(float)ci * (1.0f / 256.0f));
    float a = pos * invf;
    r[gid] = (c < 256) ? sinf(a) : cosf(a);
}

// C[M,N] = A[M,K] * B[N,K]^T (+bias, +relu).  A rows: g<M1 from A1, else A2.
// 64x64 tile, BK=16, 256 threads, 4x4 per thread.
__global__ __launch_bounds__(256) void k_gemm(
    const float* __restrict__ A1, const float* __restrict__ A2, int M1,
    const float* __restrict__ B, const float* __restrict__ bias,
    float* __restrict__ C, int M, int N, int K, int relu) {
    __shared__ float As[16][64];
    __shared__ float Bs[16][64];
    int tid = threadIdx.x;
    int bm = blockIdx.y * 64;
    int bn = blockIdx.x * 64;
    int r = tid >> 2, kq = tid & 3;
    int tm = tid >> 4, tn = tid & 15;
    float acc[4][4] = {};
    for (int k0 = 0; k0 < K; k0 += 16) {
        {
            int g = bm + r;
            float4 a = make_float4(0.f, 0.f, 0.f, 0.f);
            if (g < M) {
                const float* Ar = (g < M1) ? (A1 + (size_t)g * K)
                                           : (A2 + (size_t)(g - M1) * K);
                a = *reinterpret_cast<const float4*>(Ar + k0 + kq * 4);
            }
            As[kq * 4 + 0][r] = a.x;
            As[kq * 4 + 1][r] = a.y;
            As[kq * 4 + 2][r] = a.z;
            As[kq * 4 + 3][r] = a.w;
            int gn = bn + r;
            float4 bv = make_float4(0.f, 0.f, 0.f, 0.f);
            if (gn < N)
                bv = *reinterpret_cast<const float4*>(B + (size_t)gn * K + k0 + kq * 4);
            Bs[kq * 4 + 0][r] = bv.x;
            Bs[kq * 4 + 1][r] = bv.y;
            Bs[kq * 4 + 2][r] = bv.z;
            Bs[kq * 4 + 3][r] = bv.w;
        }
        __syncthreads();
#pragma unroll
        for (int k = 0; k < 16; ++k) {
            float4 av = *reinterpret_cast<const float4*>(&As[k][tm * 4]);
            float4 bv = *reinterpret_cast<const float4*>(&Bs[k][tn * 4]);
            float aa[4] = {av.x, av.y, av.z, av.w};
            float bb[4] = {bv.x, bv.y, bv.z, bv.w};
#pragma unroll
            for (int i2 = 0; i2 < 4; ++i2)
#pragma unroll
                for (int j2 = 0; j2 < 4; ++j2) acc[i2][j2] += aa[i2] * bb[j2];
        }
        __syncthreads();
    }
#pragma unroll
    for (int i2 = 0; i2 < 4; ++i2) {
        int gm = bm + tm * 4 + i2;
        if (gm >= M) continue;
#pragma unroll
        for (int j2 = 0; j2 < 4; ++j2) {
            int gn = bn + tn * 4 + j2;
            if (gn >= N) continue;
            float v = acc[i2][j2];
            if (bias) v += bias[gn];
            if (relu) v = fmaxf(v, 0.0f);
            C[(size_t)gm * N + gn] = v;
        }
    }
}

// One block per (i,b,n): scores (AC+BD, rel-shift folded into rhk index),
// softmax over valid j (j <= i+ML), then PV.  heads layout: row (j*BS+b),
// cols [0,512)=q [512,1024)=k [1024,1536)=v ; head n at n*64.
__global__ __launch_bounds__(256) void k_attn(
    const float* __restrict__ heads, const float* __restrict__ rhk,
    const float* __restrict__ rwb, const float* __restrict__ rrb,
    float* __restrict__ avec) {
    __shared__ float s_s[KL];
    __shared__ float s_q[2 * DHD];
    __shared__ float s_red[4];
    __shared__ float s_part[256];
    int tid = threadIdx.x;
    int wg = blockIdx.x;
    int n = wg & 7;
    int b = (wg >> 3) & 3;
    int i = wg >> 5;
    int jmax = i + ML;  // inclusive; mask kills j >= i+ML+1
    if (tid < DHD) {
        float q = heads[((size_t)(ML + i) * BS + b) * 1536 + n * DHD + tid];
        s_q[tid] = q + rwb[n * DHD + tid];
        s_q[DHD + tid] = q + rrb[n * DHD + tid];
    }
    __syncthreads();
    int w = tid >> 6, d = tid & 63;
    float qw = s_q[d], qr = s_q[DHD + d];
    int roff = QL - 1 - i;  // rel-shift: BD[i][j] uses rhk[j + QL-1-i]
    for (int j = w; j <= jmax; j += 4) {
        float kv = heads[((size_t)j * BS + b) * 1536 + 512 + n * DHD + d];
        float rv = rhk[(size_t)(j + roff) * DM + n * DHD + d];
        float p = qw * kv + qr * rv;
        p = wave_sum(p);
        if (d == 0) s_s[j] = p * 0.125f;  // scale = 1/sqrt(64)
    }
    __syncthreads();
    float lmax = -1e30f;
    for (int j = tid; j <= jmax; j += 256) lmax = fmaxf(lmax, s_s[j]);
    lmax = wave_max(lmax);
    if ((tid & 63) == 0) s_red[w] = lmax;
    __syncthreads();
    float mx = fmaxf(fmaxf(s_red[0], s_red[1]), fmaxf(s_red[2], s_red[3]));
    __syncthreads();  // protect s_red before reuse
    float lsum = 0.f;
    for (int j = tid; j <= jmax; j += 256) {
        float e = expf(s_s[j] - mx);
        s_s[j] = e;
        lsum += e;
    }
    lsum = wave_sum(lsum);
    if ((tid & 63) == 0) s_red[w] = lsum;
    __syncthreads();
    float inv = 1.0f / (s_red[0] + s_red[1] + s_red[2] + s_red[3]);
    float part = 0.f;
    for (int j = w; j <= jmax; j += 4)
        part += s_s[j] * heads[((size_t)j * BS + b) * 1536 + 1024 + n * DHD + d];
    s_part[tid] = part;
    __syncthreads();
    if (tid < 64) {
        float o = (s_part[tid] + s_part[64 + tid] + s_part[128 + tid] +
                   s_part[192 + tid]) * inv;
        avec[((size_t)i * BS + b) * DM + n * DHD + tid] = o;
    }
}

// h = LayerNorm(h + delta) * g + b  (row = one token, D=512, 2 elems/thread)
__global__ __launch_bounds__(256) void k_add_ln(
    float* __restrict__ h, const float* __restrict__ delta,
    const float* __restrict__ g, const float* __restrict__ bta) {
    __shared__ float s_red[4];
    int row = blockIdx.x;
    int tid = threadIdx.x;
    size_t base = (size_t)row * DM + tid * 2;
    float2 hv = *reinterpret_cast<const float2*>(h + base);
    float2 dv = *reinterpret_cast<const float2*>(delta + base);
    float v0 = hv.x + dv.x, v1 = hv.y + dv.y;
    float s = wave_sum(v0 + v1);
    int w = tid >> 6;
    if ((tid & 63) == 0) s_red[w] = s;
    __syncthreads();
    float mean = (s_red[0] + s_red[1] + s_red[2] + s_red[3]) * (1.0f / DM);
    __syncthreads();
    float d0 = v0 - mean, d1 = v1 - mean;
    float s2 = wave_sum(d0 * d0 + d1 * d1);
    if ((tid & 63) == 0) s_red[w] = s2;
    __syncthreads();
    float var = (s_red[0] + s_red[1] + s_red[2] + s_red[3]) * (1.0f / DM);
    float rs = rsqrtf(var + 1e-5f);
    int c = tid * 2;
    float o0 = d0 * rs * g[c] + bta[c];
    float o1 = d1 * rs * g[c + 1] + bta[c + 1];
    *reinterpret_cast<float2*>(h + base) = make_float2(o0, o1);
}

extern "C" void kernel_launch(void* const* d_in, const int* in_sizes, int n_in,
                              void* d_out, int out_size, void* d_ws, size_t ws_size,
                              hipStream_t stream) {
    const int*   x      = (const int*)d_in[0];
    const float* mems   = (const float*)d_in[1];
    const float* emb    = (const float*)d_in[2];
    const float* qkv_w  = (const float*)d_in[3];
    const float* rnet_w = (const float*)d_in[4];
    const float* o_w    = (const float*)d_in[5];
    const float* ln1_g  = (const float*)d_in[6];
    const float* ln1_b  = (const float*)d_in[7];
    const float* ff_w1  = (const float*)d_in[8];
    const float* ff_b1  = (const float*)d_in[9];
    const float* ff_w2  = (const float*)d_in[10];
    const float* ff_b2  = (const float*)d_in[11];
    const float* ln2_g  = (const float*)d_in[12];
    const float* ln2_b  = (const float*)d_in[13];
    const float* rwb    = (const float*)d_in[14];
    const float* rrb    = (const float*)d_in[15];
    const float* proj_w = (const float*)d_in[16];
    const float* proj_b = (const float*)d_in[17];
    float* out = (float*)d_out;

    // Big transient buffers live inside d_out (163 MB; final proj overwrites):
    float* heads = out;                          // 8192*1536 = 12.58M f32
    float* ffb   = out + (size_t)8192 * 1536;    // 4096*2048 =  8.39M f32
    // ws: 8.39M f32 = 33.6 MB
    float* ws   = (float*)d_ws;
    float* h    = ws;                            // 4096*512
    float* rbuf = h + (size_t)4096 * 512;        // 2048*512
    float* rhk  = rbuf + (size_t)2048 * 512;     // 2048*512
    float* avec = rhk + (size_t)2048 * 512;      // 4096*512
    float* aout = avec + (size_t)4096 * 512;     // 4096*512

    k_embed<<<2048, 256, 0, stream>>>(x, emb, h);
    k_posemb<<<4096, 256, 0, stream>>>(rbuf);

    for (int l = 0; l < LNUM; ++l) {
        const float* memsl = mems + (size_t)l * ML * BS * DM;
        // heads = cat(mems[l], h) @ qkv_w[l]^T  : (8192 x 1536)
        k_gemm<<<dim3(1536 / 64, 8192 / 64), 256, 0, stream>>>(
            memsl, h, 4096, qkv_w + (size_t)l * 1536 * DM, nullptr,
            heads, 8192, 1536, DM, 0);
        // rhk = r @ r_net_w[l]^T : (2048 x 512)
        k_gemm<<<dim3(512 / 64, 2048 / 64), 256, 0, stream>>>(
            rbuf, nullptr, 2048, rnet_w + (size_t)l * DM * DM, nullptr,
            rhk, 2048, 512, DM, 0);
        k_attn<<<QL * BS * NH, 256, 0, stream>>>(heads, rhk, rwb, rrb, avec);
        // aout = avec @ o_w[l]^T : (4096 x 512)
        k_gemm<<<dim3(512 / 64, 4096 / 64), 256, 0, stream>>>(
            avec, nullptr, 4096, o_w + (size_t)l * DM * DM, nullptr,
            aout, 4096, 512, DM, 0);
        k_add_ln<<<4096, 256, 0, stream>>>(h, aout, ln1_g + l * DM, ln1_b + l * DM);
        // ffb = relu(h @ ff_w1^T + b1) : (4096 x 2048)
        k_gemm<<<dim3(2048 / 64, 4096 / 64), 256, 0, stream>>>(
            h, nullptr, 4096, ff_w1 + (size_t)l * DFF * DM, ff_b1 + (size_t)l * DFF,
            ffb, 4096, DFF, DM, 1);
        // aout = ffb @ ff_w2^T + b2 : (4096 x 512)
        k_gemm<<<dim3(512 / 64, 4096 / 64), 256, 0, stream>>>(
            ffb, nullptr, 4096, ff_w2 + (size_t)l * DM * DFF, ff_b2 + (size_t)l * DM,
            aout, 4096, 512, DFF, 0);
        k_add_ln<<<4096, 256, 0, stream>>>(h, aout, ln2_g + l * DM, ln2_b + l * DM);
    }
    // logits = h @ proj_w^T + proj_b : (4096 x 10000) -> d_out
    k_gemm<<<dim3((NV + 63) / 64, 4096 / 64), 256, 0, stream>>>(
        h, nullptr, 4096, proj_w, proj_b, out, 4096, NV, DM, 0);
}